// Round 13
// baseline (190.289 us; speedup 1.0000x reference)
//
#include <hip/hip_runtime.h>
#include <hip/hip_bf16.h>

typedef _Float16 f16;
typedef _Float16 f16x4 __attribute__((ext_vector_type(4)));
typedef _Float16 f16x8 __attribute__((ext_vector_type(8)));
typedef float f32x4 __attribute__((ext_vector_type(4)));
typedef float f32x16 __attribute__((ext_vector_type(16)));

constexpr int BATCH = 4, C = 512, CQ = 128, N = 4096;
constexpr int FKD = 256; // f(128) + k(128) channels (conceptual; stored split below)

// workspace layout (bytes)
constexpr size_t WS_XT   = 0;                                      // f16 [B][N][C]        16 MB
constexpr size_t WS_FT   = WS_XT   + (size_t)BATCH * N * C * 2;    // f16 [B][N][128]       4 MB
constexpr size_t WS_KT   = WS_FT   + (size_t)BATCH * N * CQ * 2;   // f16 [B][N/4][4][128]  4 MB (tiled K)
constexpr size_t WS_V    = WS_KT   + (size_t)BATCH * N * CQ * 2;   // f16 [B][C/16][N/8][16][8] 16 MB (tiled V)
constexpr size_t WS_WCAT = WS_V    + (size_t)BATCH * C * N * 2;    // f16 [256][512]
constexpr size_t WS_WL   = WS_WCAT + (size_t)FKD * C * 2;          // f16 [512][512]
constexpr size_t WS_BC   = WS_WL   + (size_t)C * C * 2;            // f32 [256]

// ---------------------------------------------------------------- weights->fp16
__global__ void prep_weights(const float* __restrict__ Wf_w, const float* __restrict__ Wf_b,
                             const float* __restrict__ Wh_w, const float* __restrict__ Wh_b,
                             const float* __restrict__ Wl_w,
                             f16* __restrict__ wcat, f16* __restrict__ wl, float* __restrict__ bcat) {
    int i = blockIdx.x * 256 + threadIdx.x;                 // grid covers C*C
    if (i < FKD * C) {
        int o = i >> 9, c = i & 511;
        float v = (o < CQ) ? Wf_w[o * C + c] : Wh_w[(o - CQ) * C + c];
        wcat[i] = (f16)v;
    }
    if (i < C * C) wl[i] = (f16)Wl_w[i];
    if (i < FKD) bcat[i] = (i < CQ) ? Wf_b[i] : Wh_b[i - CQ];
}

// ---------------------------------------------------------------- x (B,C,N) f32 -> xT (B,N,C) f16
__global__ void transpose_x(const float* __restrict__ x, f16* __restrict__ xt) {
    __shared__ float tile[64][65];
    int gid = blockIdx.x;
    int b = gid >> 9, rem = gid & 511;
    int c0 = (rem >> 6) * 64, n0 = (rem & 63) * 64;
    int t = threadIdx.x;
    int tn = t & 63, tg = t >> 6;
    const float* xp = x + (size_t)b * C * N + (size_t)c0 * N + n0;
#pragma unroll
    for (int r = 0; r < 16; ++r) {
        int cl = tg + r * 4;
        tile[cl][tn] = xp[(size_t)cl * N + tn];
    }
    __syncthreads();
    f16* xo = xt + (size_t)b * N * C + (size_t)n0 * C + c0;
#pragma unroll
    for (int r = 0; r < 16; ++r) {
        int nl = tg + r * 4;
        xo[(size_t)nl * C + tn] = (f16)tile[tn][nl];
    }
}

// ---------------------------------------------------------------- FK projection (64n x 64o per wave)
__global__ void __launch_bounds__(256) proj_fk(const f16* __restrict__ xt, const f16* __restrict__ wcat,
                                               const float* __restrict__ bcat,
                                               f16* __restrict__ ft, f16* __restrict__ kt) {
    int wid = blockIdx.x * 4 + (threadIdx.x >> 6);   // 1024 waves: b(2) nt(6) ot(2)
    int lane = threadIdx.x & 63;
    int li = lane & 15, lg = lane >> 4;
    int b  = wid >> 8;
    int nt = (wid >> 2) & 63;
    int ot = wid & 3;
    int n0 = nt * 64, o0 = ot * 64;
    const f16* ap = xt + (size_t)(b * N + n0 + li) * C + lg * 8;
    const f16* bp = wcat + (size_t)(o0 + li) * C + lg * 8;
    f32x4 acc[4][4] = {};
    for (int ks = 0; ks < 16; ++ks) {
        f16x8 a4[4], b4[4];
#pragma unroll
        for (int t = 0; t < 4; ++t) a4[t] = *(const f16x8*)(ap + (size_t)(t * 16) * C + ks * 32);
#pragma unroll
        for (int t = 0; t < 4; ++t) b4[t] = *(const f16x8*)(bp + (size_t)(t * 16) * C + ks * 32);
#pragma unroll
        for (int tA = 0; tA < 4; ++tA)
#pragma unroll
            for (int tB = 0; tB < 4; ++tB)
                acc[tA][tB] = __builtin_amdgcn_mfma_f32_16x16x32_f16(a4[tA], b4[tB], acc[tA][tB], 0, 0, 0);
    }
#pragma unroll
    for (int tB = 0; tB < 4; ++tB) {
        int o = o0 + tB * 16 + li;
        float bias = bcat[o];
        if (o < CQ) {
#pragma unroll
            for (int tA = 0; tA < 4; ++tA)
#pragma unroll
                for (int r = 0; r < 4; ++r) {
                    int n = n0 + tA * 16 + lg * 4 + r;
                    ft[((size_t)(b * N + n)) * CQ + o] = (f16)(acc[tA][tB][r] + bias);
                }
        } else {
            int ck = o - CQ;
#pragma unroll
            for (int tA = 0; tA < 4; ++tA)
#pragma unroll
                for (int r = 0; r < 4; ++r) {
                    int n = n0 + tA * 16 + lg * 4 + r;
                    kt[(((size_t)b * (N >> 2) + (n >> 2)) * 4 + (n & 3)) * 128 + ck] = (f16)(acc[tA][tB][r] + bias);
                }
        }
    }
}

// ---------------------------------------------------------------- V projection (64c x 64n per wave)
// output tiled: v[b][cp][jb][cl][jl]: cp=c>>4, cl=c&15, jb=n>>3, jl=n&7
__global__ void __launch_bounds__(256) proj_v(const f16* __restrict__ xt, const f16* __restrict__ wl,
                                              const float* __restrict__ wlb, f16* __restrict__ v) {
    int wid = blockIdx.x * 4 + (threadIdx.x >> 6);   // 2048 waves: b(2) ct(3) nt(6)
    int lane = threadIdx.x & 63;
    int li = lane & 15, lg = lane >> 4;
    int b  = wid >> 9;
    int ct = (wid >> 6) & 7;
    int nt = wid & 63;
    int c0 = ct * 64, n0 = nt * 64;
    const f16* ap = wl + (size_t)(c0 + li) * C + lg * 8;
    const f16* bp = xt + (size_t)(b * N + n0 + li) * C + lg * 8;
    f32x4 acc[4][4] = {};
    for (int ks = 0; ks < 16; ++ks) {
        f16x8 a4[4], b4[4];
#pragma unroll
        for (int t = 0; t < 4; ++t) a4[t] = *(const f16x8*)(ap + (size_t)(t * 16) * C + ks * 32);
#pragma unroll
        for (int t = 0; t < 4; ++t) b4[t] = *(const f16x8*)(bp + (size_t)(t * 16) * C + ks * 32);
#pragma unroll
        for (int tA = 0; tA < 4; ++tA)
#pragma unroll
            for (int tB = 0; tB < 4; ++tB)
                acc[tA][tB] = __builtin_amdgcn_mfma_f32_16x16x32_f16(a4[tA], b4[tB], acc[tA][tB], 0, 0, 0);
    }
#pragma unroll
    for (int tA = 0; tA < 4; ++tA)
#pragma unroll
        for (int r = 0; r < 4; ++r) {
            int c = c0 + tA * 16 + lg * 4 + r;
            float bias = wlb[c];
            const size_t cpb = ((size_t)b * 32 + (c >> 4)) * 512;
            const int cl = c & 15;
#pragma unroll
            for (int tB = 0; tB < 4; ++tB) {
                int n = n0 + tB * 16 + li;
                v[(cpb + (n >> 3)) * 128 + cl * 8 + (n & 7)] = (f16)(acc[tA][tB][r] + bias);
            }
        }
}

// ---------------------------------------------------------------- flash attention + residual (v13)
// v12 schedule verbatim, MFMA switched to 32x32x16. Wave decomposition:
//   QK: wj=wv&3 j-slice [wj*32,+32), wi=wv>>2 i-half [wi*32,+32): 8 MFMA, 1 acc tile
//   PV: wc=wv&3 c-group [wc*128,+128) (4 tiles of 32c), same wi: 32 MFMA
// Lane owns ONE query i = i0+wi*32+(lane&31): softmax = 15 fmax + 1 shfl; ms/ls scalar.
// C/D mapping (verified m74/m101): col=lane&31, row=(reg&3)+8*(reg>>2)+4*(lane>>5).
// A/B k-mapping gauge-invariant (both operands use k=(lane>>5)*8+e).
__global__ void __launch_bounds__(512, 2) attn(const f16* __restrict__ ft, const f16* __restrict__ kt,
                                               const f16* __restrict__ v,
                                               const float* __restrict__ x, const float* __restrict__ alphap,
                                               float* __restrict__ out) {
    __shared__ __align__(16) f16 kbuf[2][128 * 128];   // 64 KB K tile, double-buffered
    __shared__ __align__(16) f16 pbuf[64 * 128];       // 16 KB shared P
    __shared__ float smax[4][2][32];
    __shared__ float ssum[4][2][32];

    const int tid  = threadIdx.x;
    const int wv   = tid >> 6;
    const int lane = tid & 63;
    const int li = lane & 15, lg = lane >> 4;     // staging decode
    const int l31 = lane & 31, lh = lane >> 5;    // 32x32 decode
    const int sw = l31 & 7;                       // row-XOR swizzle key
    const int wj = wv & 3;                        // QK j-slice / PV c-group
    const int wi = wv >> 2;                       // i-half
    // XCD-pinning: under blk%8 round-robin, each XCD sees a single batch
    const int v0 = blockIdx.x;
    const int b  = (v0 & 7) >> 1;
    const int it = ((v0 & 1) << 5) | (v0 >> 3);
    const int i0 = it * 64;

    // F fragments (B operand of swapped QK): col=i=l31 (own i-half), k=ks*16+lh*8+e
    f16x8 fb[8];
    {
        const f16* fp = ft + (size_t)(b * N + i0 + wi * 32 + l31) * CQ + lh * 8;
#pragma unroll
        for (int ks = 0; ks < 8; ++ks) fb[ks] = *(const f16x8*)(fp + ks * 16);
    }

    // K staging from tiled kt (v12 pattern): instr k covers rows wv*16+k*4+lg,
    // granule li contiguous 1KB; LDS write XOR ^(row&7); readers XOR with row&7.
    const f16* ktb = kt + (size_t)b * N * 128;
    {   // prologue: stage tile 0 -> kbuf[0]
#pragma unroll
        for (int k = 0; k < 4; ++k) {
            f16x8 vv = *(const f16x8*)(ktb + (((size_t)(wv * 4 + k)) * 4 + lg) * 128 + li * 8);
            *(f16x8*)(&kbuf[0][(wv * 16 + k * 4 + lg) * 128 + ((li ^ ((k * 4 + lg) & 7)) * 8)]) = vv;
        }
    }

    // tiled V per-lane base: c = wj*128 + ct*32 + l31 -> cp = wj*8 + ct*2 + (l31>>4)
    const f16* vL = v + (((size_t)b * 32 + wj * 8 + (l31 >> 4)) * 512 + lh) * 128 + (l31 & 15) * 8;
    const int prow = wi * 32 + l31;               // pbuf row (query)
    f32x16 oacc[4] = {};                          // [c-tile of 32]
    float ms = -1e30f, ls = 0.f;
    __syncthreads();

    for (int t = 0; t < 32; ++t) {
        const f16* kc = &kbuf[t & 1][0];
        f16*       kn = &kbuf[(t + 1) & 1][0];
        // (a) issue next K-tile global loads early
        const int gn = (t < 31) ? (t + 1) * 32 : 0;
        f16x8 stg[4];
#pragma unroll
        for (int k = 0; k < 4; ++k)
            stg[k] = *(const f16x8*)(ktb + (((size_t)(gn + wv * 4 + k)) * 4 + lg) * 128 + li * 8);

        // (b) QK: S^T tile (32j x 32i) = mfma(A=K, B=F), 8 k-steps
        f32x16 s = {};
        __builtin_amdgcn_s_setprio(1);
#pragma unroll
        for (int ks = 0; ks < 8; ++ks) {
            f16x8 kf = *(const f16x8*)(&kc[(wj * 32 + l31) * 128 + (((ks * 2 + lh) ^ sw) * 8)]);
            s = __builtin_amdgcn_mfma_f32_32x32x16_f16(kf, fb[ks], s, 0, 0, 0);
        }
        __builtin_amdgcn_s_setprio(0);

        // (c) wave-local max for own query (16 values + cross-half shfl)
        float tm = s[0];
#pragma unroll
        for (int r = 1; r < 16; ++r) tm = fmaxf(tm, s[r]);
        tm = fmaxf(tm, __shfl_xor(tm, 32));
        if (lane < 32) smax[wj][wi][l31] = tm;
        // V prefetch js=0 (4 c-tiles), before the barrier
        f16x8 vaA[4], vaB[4];
#pragma unroll
        for (int ct = 0; ct < 4; ++ct) vaA[ct] = *(const f16x8*)(vL + ((size_t)(ct * 1024 + t * 16)) * 128);
        __syncthreads();   // B1: smax visible
        // (d) global max over 4 j-slices + T13 deferred rescale
        float gm = fmaxf(fmaxf(smax[0][wi][l31], smax[1][wi][l31]),
                         fmaxf(smax[2][wi][l31], smax[3][wi][l31]));
        if (!__all(gm <= ms + 8.0f)) {
            float mn = fmaxf(ms, gm), sc = __expf(ms - mn);
            ms = mn; ls *= sc;
#pragma unroll
            for (int ct = 0; ct < 4; ++ct) oacc[ct] *= sc;
        }
        // V prefetch js=1
#pragma unroll
        for (int ct = 0; ct < 4; ++ct) vaB[ct] = *(const f16x8*)(vL + ((size_t)(ct * 1024 + t * 16 + 2)) * 128);
        // (e) exp + P write (rows = own query; j = wj*32 + q*8 + lh*4 + r) + partial sum
        float psum = 0.f;
#pragma unroll
        for (int q = 0; q < 4; ++q) {
            f16x4 pk;
#pragma unroll
            for (int r = 0; r < 4; ++r) { float p = __expf(s[q * 4 + r] - ms); psum += p; pk[r] = (f16)p; }
            const int g = (wj * 4 + q) ^ sw;
            *(f16x4*)(&pbuf[prow * 128 + g * 8 + lh * 4]) = pk;
        }
        psum += __shfl_xor(psum, 32);
        if (lane < 32) ssum[wj][wi][l31] = psum;
        // write staged K tile to next buffer
#pragma unroll
        for (int k = 0; k < 4; ++k)
            *(f16x8*)(&kn[(wv * 16 + k * 4 + lg) * 128 + ((li ^ ((k * 4 + lg) & 7)) * 8)]) = stg[k];
        __syncthreads();   // B2: P + ssum + next-K visible
        // (f) accumulate l over 4 j-slices
        ls += ssum[0][wi][l31] + ssum[1][wi][l31] + ssum[2][wi][l31] + ssum[3][wi][l31];
        // (g) PV: 8 j-steps of 16; own c-group (4 tiles) x own i-half; rolling V prefetch
#pragma unroll
        for (int js = 0; js < 8; ++js) {
            f16x8 pb = *(const f16x8*)(&pbuf[prow * 128 + (((js * 2 + lh) ^ sw) * 8)]);
            f16x8 vv0, vv1, vv2, vv3;
            if (js & 1) { vv0 = vaB[0]; vv1 = vaB[1]; vv2 = vaB[2]; vv3 = vaB[3]; }
            else        { vv0 = vaA[0]; vv1 = vaA[1]; vv2 = vaA[2]; vv3 = vaA[3]; }
            if (js < 6) {
#pragma unroll
                for (int ct = 0; ct < 4; ++ct) {
                    f16x8 nv = *(const f16x8*)(vL + ((size_t)(ct * 1024 + t * 16 + (js + 2) * 2)) * 128);
                    if (js & 1) vaB[ct] = nv; else vaA[ct] = nv;
                }
            }
            __builtin_amdgcn_s_setprio(1);
            oacc[0] = __builtin_amdgcn_mfma_f32_32x32x16_f16(vv0, pb, oacc[0], 0, 0, 0);
            oacc[1] = __builtin_amdgcn_mfma_f32_32x32x16_f16(vv1, pb, oacc[1], 0, 0, 0);
            oacc[2] = __builtin_amdgcn_mfma_f32_32x32x16_f16(vv2, pb, oacc[2], 0, 0, 0);
            oacc[3] = __builtin_amdgcn_mfma_f32_32x32x16_f16(vv3, pb, oacc[3], 0, 0, 0);
            __builtin_amdgcn_s_setprio(0);
        }
        // no 3rd barrier: next iter's B1 orders pbuf/kbuf reuse
    }

    // epilogue: O[c][i], 32 consecutive i per row (full 128B lines); + residual
    const float alpha = alphap[0];
    const float inv = alpha / ls;
    const int icol = i0 + wi * 32 + l31;
#pragma unroll
    for (int ct = 0; ct < 4; ++ct)
#pragma unroll
        for (int r = 0; r < 16; ++r) {
            const int c = wj * 128 + ct * 32 + (r & 3) + 8 * (r >> 2) + 4 * lh;
            const size_t off = (size_t)(b * C + c) * N + icol;
            out[off] = oacc[ct][r] * inv + x[off];
        }
}

extern "C" void kernel_launch(void* const* d_in, const int* in_sizes, int n_in,
                              void* d_out, int out_size, void* d_ws, size_t ws_size,
                              hipStream_t stream) {
    const float* x     = (const float*)d_in[0];
    const float* Wf_w  = (const float*)d_in[1];
    const float* Wf_b  = (const float*)d_in[2];
    const float* Wh_w  = (const float*)d_in[3];
    const float* Wh_b  = (const float*)d_in[4];
    const float* Wl_w  = (const float*)d_in[5];
    const float* Wl_b  = (const float*)d_in[6];
    const float* alpha = (const float*)d_in[7];
    char* ws = (char*)d_ws;
    f16*   xt   = (f16*)(ws + WS_XT);
    f16*   ftb  = (f16*)(ws + WS_FT);
    f16*   ktb  = (f16*)(ws + WS_KT);
    f16*   vb   = (f16*)(ws + WS_V);
    f16*   wcat = (f16*)(ws + WS_WCAT);
    f16*   wl   = (f16*)(ws + WS_WL);
    float* bcat = (float*)(ws + WS_BC);
    float* out  = (float*)d_out;

    prep_weights<<<dim3((C * C + 255) / 256), dim3(256), 0, stream>>>(Wf_w, Wf_b, Wh_w, Wh_b, Wl_w, wcat, wl, bcat);
    transpose_x<<<dim3(BATCH * 8 * 64), dim3(256), 0, stream>>>(x, xt);
    proj_fk<<<dim3(256), dim3(256), 0, stream>>>(xt, wcat, bcat, ftb, ktb);
    proj_v<<<dim3(512), dim3(256), 0, stream>>>(xt, wl, Wl_b, vb);
    // 4 b x 64 query-tiles(64q) = 256 blocks x 8 waves = 1 block/CU, XCD-pinned
    attn<<<dim3(256), dim3(512), 0, stream>>>(ftb, ktb, vb, x, alpha, out);
}